// Round 1
// baseline (300.333 us; speedup 1.0000x reference)
//
#include <hip/hip_runtime.h>
#include <hip/hip_bf16.h>

typedef __bf16 b16x8 __attribute__((ext_vector_type(8)));
typedef unsigned short u16x8 __attribute__((ext_vector_type(8)));
typedef unsigned short u16x4 __attribute__((ext_vector_type(4)));
typedef float f32x4 __attribute__((ext_vector_type(4)));

__device__ __forceinline__ unsigned short f2b(float f) {
  unsigned u = __builtin_bit_cast(unsigned, f);
  u += 0x7fff + ((u >> 16) & 1);   // round-to-nearest-even
  return (unsigned short)(u >> 16);
}

__device__ __forceinline__ b16x8 as_b(u16x8 v) { return __builtin_bit_cast(b16x8, v); }

// ---------------------------------------------------------------------------
// GEMM: C[M][N] = A[M][K] * W[N][K]^T + bias[N]
// 128x128 tile, BK=64, 4 waves (2x2), each wave 64x64 via 4x4 frags of 16x16x32.
// LDS XOR-swizzled: ushort idx ^= (row&7)<<3  (16B-slot swizzle within 128B row).
// ---------------------------------------------------------------------------
template <int TIN_BYTES, typename TOUT>
__device__ __forceinline__ void gemm_body(const void* __restrict__ Av,
                                          const float* __restrict__ W,
                                          const float* __restrict__ bias,
                                          TOUT* __restrict__ C,
                                          int K, int N) {
  __shared__ __align__(16) unsigned short sA[128 * 64];
  __shared__ __align__(16) unsigned short sB[128 * 64];
  const int tid = threadIdx.x;
  const int lane = tid & 63, wid = tid >> 6;
  const int wm = wid >> 1, wn = wid & 1;
  const int lr = lane & 15, lg = lane >> 4;
  const int bm = blockIdx.y * 128, bn = blockIdx.x * 128;
  const int srow = tid >> 1, shalf = (tid & 1) * 32;   // staging: row 0..127, k-half

  f32x4 acc[4][4] = {};

  for (int k0 = 0; k0 < K; k0 += 64) {
    // stage A (convert fp32 -> bf16 if needed)
    if constexpr (TIN_BYTES == 4) {
      const float* src = (const float*)Av + (size_t)(bm + srow) * K + k0 + shalf;
#pragma unroll
      for (int u = 0; u < 8; ++u) {
        float4 f = *(const float4*)(src + u * 4);
        u16x4 h = { f2b(f.x), f2b(f.y), f2b(f.z), f2b(f.w) };
        int idx = (srow * 64 + shalf + u * 4) ^ ((srow & 7) << 3);
        *(u16x4*)(&sA[idx]) = h;
      }
    } else {
      const unsigned short* src = (const unsigned short*)Av + (size_t)(bm + srow) * K + k0 + shalf;
#pragma unroll
      for (int u = 0; u < 4; ++u) {
        u16x8 hv = *(const u16x8*)(src + u * 8);
        int idx = (srow * 64 + shalf + u * 8) ^ ((srow & 7) << 3);
        *(u16x8*)(&sA[idx]) = hv;
      }
    }
    // stage W (always fp32 [N][K])
    {
      const float* src = W + (size_t)(bn + srow) * K + k0 + shalf;
#pragma unroll
      for (int u = 0; u < 8; ++u) {
        float4 f = *(const float4*)(src + u * 4);
        u16x4 h = { f2b(f.x), f2b(f.y), f2b(f.z), f2b(f.w) };
        int idx = (srow * 64 + shalf + u * 4) ^ ((srow & 7) << 3);
        *(u16x4*)(&sB[idx]) = h;
      }
    }
    __syncthreads();

    b16x8 af[4][2], bf[4][2];
#pragma unroll
    for (int mb = 0; mb < 4; ++mb)
#pragma unroll
      for (int kh = 0; kh < 2; ++kh) {
        int r = wm * 64 + mb * 16 + lr;
        int idx = (r * 64 + kh * 32 + lg * 8) ^ ((r & 7) << 3);
        af[mb][kh] = as_b(*(const u16x8*)(&sA[idx]));
      }
#pragma unroll
    for (int nb = 0; nb < 4; ++nb)
#pragma unroll
      for (int kh = 0; kh < 2; ++kh) {
        int r = wn * 64 + nb * 16 + lr;
        int idx = (r * 64 + kh * 32 + lg * 8) ^ ((r & 7) << 3);
        bf[nb][kh] = as_b(*(const u16x8*)(&sB[idx]));
      }
#pragma unroll
    for (int mb = 0; mb < 4; ++mb)
#pragma unroll
      for (int nb = 0; nb < 4; ++nb) {
        acc[mb][nb] = __builtin_amdgcn_mfma_f32_16x16x32_bf16(af[mb][0], bf[nb][0], acc[mb][nb], 0, 0, 0);
        acc[mb][nb] = __builtin_amdgcn_mfma_f32_16x16x32_bf16(af[mb][1], bf[nb][1], acc[mb][nb], 0, 0, 0);
      }
    __syncthreads();
  }

  // epilogue: D layout col = lane&15, row = (lane>>4)*4 + i
#pragma unroll
  for (int mb = 0; mb < 4; ++mb)
#pragma unroll
    for (int nb = 0; nb < 4; ++nb) {
      int c = bn + wn * 64 + nb * 16 + lr;
      float bv = bias[c];
      int r0 = bm + wm * 64 + mb * 16 + lg * 4;
#pragma unroll
      for (int i = 0; i < 4; ++i) {
        float val = acc[mb][nb][i] + bv;
        if constexpr (sizeof(TOUT) == 2) C[(size_t)(r0 + i) * N + c] = f2b(val);
        else C[(size_t)(r0 + i) * N + c] = val;
      }
    }
}

__global__ __launch_bounds__(256) void proj_kernel(
    const float* __restrict__ q, const float* __restrict__ k, const float* __restrict__ v,
    const float* __restrict__ Wq, const float* __restrict__ bq,
    const float* __restrict__ Wk, const float* __restrict__ bk,
    const float* __restrict__ Wv, const float* __restrict__ bv,
    unsigned short* __restrict__ Qh, unsigned short* __restrict__ Kh,
    unsigned short* __restrict__ Vh) {
  const float* A; const float* W; const float* B; unsigned short* C;
  if (blockIdx.z == 0)      { A = q; W = Wq; B = bq; C = Qh; }
  else if (blockIdx.z == 1) { A = k; W = Wk; B = bk; C = Kh; }
  else                      { A = v; W = Wv; B = bv; C = Vh; }
  gemm_body<4, unsigned short>(A, W, B, C, 1024, 1024);
}

__global__ __launch_bounds__(256) void out_kernel(
    const unsigned short* __restrict__ X, const float* __restrict__ Wo,
    const float* __restrict__ bo, float* __restrict__ out) {
  gemm_body<2, float>(X, Wo, bo, out, 1024, 1024);
}

// ---------------------------------------------------------------------------
// Flash attention: grid (TQ/64, B*H). 4 waves, wave owns 16 q-rows.
// KV tiles of 64 staged in LDS (K row-major, V transposed), online softmax.
// ---------------------------------------------------------------------------
__global__ __launch_bounds__(256) void attn_kernel(
    const unsigned short* __restrict__ Qh, const unsigned short* __restrict__ Kh,
    const unsigned short* __restrict__ Vh, unsigned short* __restrict__ X) {
  __shared__ __align__(16) unsigned short sQ[64 * 64];
  __shared__ __align__(16) unsigned short sK[64 * 64];
  __shared__ __align__(16) unsigned short sV[64 * 64];     // transposed: [hd][kv]
  __shared__ __align__(16) unsigned short sP[4][16 * 64];  // per wave

  const int tid = threadIdx.x;
  const int lane = tid & 63, wid = tid >> 6;
  const int lr = lane & 15, lg = lane >> 4;
  const int b = blockIdx.y >> 4, h = blockIdx.y & 15;
  const int q0 = blockIdx.x * 64;
  const size_t base = (size_t)b * 2048 * 1024 + (size_t)h * 64;

  const int srow = tid >> 2, sseg = tid & 3;   // staging: row 0..63, 16-elem segment

  // stage Q tile (64 rows x 64 hd)
  {
    const unsigned short* src = Qh + base + (size_t)(q0 + srow) * 1024 + sseg * 16;
#pragma unroll
    for (int u = 0; u < 2; ++u) {
      u16x8 vv = *(const u16x8*)(src + u * 8);
      int idx = (srow * 64 + sseg * 16 + u * 8) ^ ((srow & 7) << 3);
      *(u16x8*)(&sQ[idx]) = vv;
    }
  }
  __syncthreads();
  b16x8 qf[2];
  {
    int r = wid * 16 + lr;
#pragma unroll
    for (int kh = 0; kh < 2; ++kh) {
      int idx = (r * 64 + kh * 32 + lg * 8) ^ ((r & 7) << 3);
      qf[kh] = as_b(*(const u16x8*)(&sQ[idx]));
    }
  }

  float m_r[4], l_r[4];
  f32x4 acc[4] = {};
#pragma unroll
  for (int i = 0; i < 4; ++i) { m_r[i] = -1e30f; l_r[i] = 0.f; }

  for (int kv0 = 0; kv0 < 2048; kv0 += 64) {
    // stage K tile
    {
      const unsigned short* src = Kh + base + (size_t)(kv0 + srow) * 1024 + sseg * 16;
#pragma unroll
      for (int u = 0; u < 2; ++u) {
        u16x8 vv = *(const u16x8*)(src + u * 8);
        int idx = (srow * 64 + sseg * 16 + u * 8) ^ ((srow & 7) << 3);
        *(u16x8*)(&sK[idx]) = vv;
      }
    }
    // stage V tile transposed ([hd][kv], swizzled)
    {
      const unsigned short* src = Vh + base + (size_t)(kv0 + srow) * 1024 + sseg * 16;
      u16x8 v0 = *(const u16x8*)(src);
      u16x8 v1 = *(const u16x8*)(src + 8);
#pragma unroll
      for (int e = 0; e < 8; ++e) {
        int hd = sseg * 16 + e;
        sV[(hd * 64 + srow) ^ ((hd & 7) << 3)] = v0[e];
      }
#pragma unroll
      for (int e = 0; e < 8; ++e) {
        int hd = sseg * 16 + 8 + e;
        sV[(hd * 64 + srow) ^ ((hd & 7) << 3)] = v1[e];
      }
    }
    __syncthreads();

    // S = Q * K^T   (4 kv-blocks of 16, contract over hd=64)
    f32x4 s[4];
#pragma unroll
    for (int kb = 0; kb < 4; ++kb) {
      int kvr = kb * 16 + lr;
      int i0 = (kvr * 64 + lg * 8) ^ ((kvr & 7) << 3);
      int i1 = (kvr * 64 + 32 + lg * 8) ^ ((kvr & 7) << 3);
      b16x8 kf0 = as_b(*(const u16x8*)(&sK[i0]));
      b16x8 kf1 = as_b(*(const u16x8*)(&sK[i1]));
      f32x4 z = {};
      z = __builtin_amdgcn_mfma_f32_16x16x32_bf16(qf[0], kf0, z, 0, 0, 0);
      s[kb] = __builtin_amdgcn_mfma_f32_16x16x32_bf16(qf[1], kf1, z, 0, 0, 0);
    }

    // online softmax (rows = lg*4+i, spread over 16 lanes lr)
    const float scale = 0.125f;
    float al[4];
#pragma unroll
    for (int i = 0; i < 4; ++i) {
      float mx = fmaxf(fmaxf(s[0][i], s[1][i]), fmaxf(s[2][i], s[3][i]));
      mx = fmaxf(mx, __shfl_xor(mx, 1));
      mx = fmaxf(mx, __shfl_xor(mx, 2));
      mx = fmaxf(mx, __shfl_xor(mx, 4));
      mx = fmaxf(mx, __shfl_xor(mx, 8));
      float mn = fmaxf(m_r[i], mx * scale);
      al[i] = __expf(m_r[i] - mn);
      m_r[i] = mn;
    }
    float p[4][4];   // [kb][i]
#pragma unroll
    for (int i = 0; i < 4; ++i) {
      float sum = 0.f;
#pragma unroll
      for (int kb = 0; kb < 4; ++kb) {
        float pv = __expf(s[kb][i] * scale - m_r[i]);
        p[kb][i] = pv;
        sum += pv;
      }
      sum += __shfl_xor(sum, 1);
      sum += __shfl_xor(sum, 2);
      sum += __shfl_xor(sum, 4);
      sum += __shfl_xor(sum, 8);
      l_r[i] = l_r[i] * al[i] + sum;
#pragma unroll
      for (int hb = 0; hb < 4; ++hb) acc[hb][i] *= al[i];
    }

    // bounce P through per-wave LDS to re-fragment (D-layout -> A-layout)
    unsigned short* myP = &sP[wid][0];
#pragma unroll
    for (int i = 0; i < 4; ++i) {
      int qr = lg * 4 + i;
#pragma unroll
      for (int kb = 0; kb < 4; ++kb) {
        myP[(qr * 64 + kb * 16 + lr) ^ ((qr & 7) << 3)] = f2b(p[kb][i]);
      }
    }
    b16x8 pa[2];
#pragma unroll
    for (int half = 0; half < 2; ++half) {
      int idx = (lr * 64 + half * 32 + lg * 8) ^ ((lr & 7) << 3);
      pa[half] = as_b(*(const u16x8*)(&myP[idx]));
    }

    // O += P * V   (4 hd-blocks of 16, contract over kv=64)
#pragma unroll
    for (int hb = 0; hb < 4; ++hb) {
      int hr = hb * 16 + lr;
      int i0 = (hr * 64 + lg * 8) ^ ((hr & 7) << 3);
      int i1 = (hr * 64 + 32 + lg * 8) ^ ((hr & 7) << 3);
      b16x8 vf0 = as_b(*(const u16x8*)(&sV[i0]));
      b16x8 vf1 = as_b(*(const u16x8*)(&sV[i1]));
      acc[hb] = __builtin_amdgcn_mfma_f32_16x16x32_bf16(pa[0], vf0, acc[hb], 0, 0, 0);
      acc[hb] = __builtin_amdgcn_mfma_f32_16x16x32_bf16(pa[1], vf1, acc[hb], 0, 0, 0);
    }
    __syncthreads();
  }

  // epilogue: normalize and write x (head-interleaved [B][T][1024])
#pragma unroll
  for (int hb = 0; hb < 4; ++hb) {
#pragma unroll
    for (int i = 0; i < 4; ++i) {
      int qr = q0 + wid * 16 + lg * 4 + i;
      int hd = hb * 16 + lr;
      float val = acc[hb][i] / l_r[i];
      X[base + (size_t)qr * 1024 + hd] = f2b(val);
    }
  }
}

extern "C" void kernel_launch(void* const* d_in, const int* in_sizes, int n_in,
                              void* d_out, int out_size, void* d_ws, size_t ws_size,
                              hipStream_t stream) {
  const float* q  = (const float*)d_in[0];
  const float* k  = (const float*)d_in[1];
  const float* v  = (const float*)d_in[2];
  const float* Wq = (const float*)d_in[3];
  const float* bq = (const float*)d_in[4];
  const float* Wk = (const float*)d_in[5];
  const float* bk = (const float*)d_in[6];
  const float* Wv = (const float*)d_in[7];
  const float* bv = (const float*)d_in[8];
  const float* Wo = (const float*)d_in[9];
  const float* bo = (const float*)d_in[10];

  unsigned short* Qh = (unsigned short*)d_ws;
  unsigned short* Kh = Qh + (size_t)4096 * 1024;
  unsigned short* Vh = Kh + (size_t)4096 * 1024;
  unsigned short* X  = Vh + (size_t)4096 * 1024;

  dim3 blk(256);
  proj_kernel<<<dim3(8, 32, 3), blk, 0, stream>>>(q, k, v, Wq, bq, Wk, bk, Wv, bv, Qh, Kh, Vh);
  attn_kernel<<<dim3(32, 32), blk, 0, stream>>>(Qh, Kh, Vh, X);
  out_kernel<<<dim3(8, 32), blk, 0, stream>>>(X, Wo, bo, (float*)d_out);
}

// Round 3
// 252.126 us; speedup vs baseline: 1.1912x; 1.1912x over previous
//
#include <hip/hip_runtime.h>
#include <hip/hip_bf16.h>

typedef __bf16 b16x8 __attribute__((ext_vector_type(8)));
typedef unsigned short u16x8 __attribute__((ext_vector_type(8)));
typedef unsigned short u16x4 __attribute__((ext_vector_type(4)));
typedef unsigned int u32x4 __attribute__((ext_vector_type(4)));
typedef float f32x4 __attribute__((ext_vector_type(4)));
typedef float f32x16 __attribute__((ext_vector_type(16)));

__device__ __forceinline__ unsigned short f2b(float f) {
  unsigned u = __builtin_bit_cast(unsigned, f);
  u += 0x7fff + ((u >> 16) & 1);   // round-to-nearest-even
  return (unsigned short)(u >> 16);
}

__device__ __forceinline__ b16x8 as_b(u16x8 v) { return __builtin_bit_cast(b16x8, v); }

__device__ __forceinline__ float fexp2(float x) {
#if __has_builtin(__builtin_amdgcn_exp2f)
  return __builtin_amdgcn_exp2f(x);
#else
  return exp2f(x);
#endif
}

__device__ __forceinline__ unsigned pk2(float lo, float hi) {
  return (unsigned)f2b(lo) | ((unsigned)f2b(hi) << 16);
}

__device__ __forceinline__ void plswap(unsigned& a, unsigned& b) {
  asm volatile("v_permlane32_swap_b32 %0, %1" : "+v"(a), "+v"(b));
}

// Build one 16-wide kv chunk (A/B-frag for 32x32x16) from 8 exp'd P values.
// Lane layout in: p[j] = P[q=lane&31][kv = (j&3)+8*(j>>2)+4*(lane>>5) (+base)]
// Lane layout out: elem e = P[q][kv = 8*(lane>>5)+e (+base)]
__device__ __forceinline__ b16x8 mkchunk(float p0, float p1, float p2, float p3,
                                         float p4, float p5, float p6, float p7) {
  unsigned a1 = pk2(p0, p1), b1 = pk2(p4, p5);
  unsigned a2 = pk2(p2, p3), b2 = pk2(p6, p7);
  plswap(a1, b1);
  plswap(a2, b2);
  u32x4 w = {a1, a2, b1, b2};
  return __builtin_bit_cast(b16x8, w);
}

#define AS1 __attribute__((address_space(1)))
#define AS3 __attribute__((address_space(3)))
__device__ __forceinline__ void gload_lds16(const void* g, void* l) {
  __builtin_amdgcn_global_load_lds((const AS1 void*)g, (AS3 void*)l, 16, 0, 0);
}

// ---------------------------------------------------------------------------
// GEMM: C[M][N] = A[M][K] * W[N][K]^T + bias[N]
// MODE 0: bf16 out natural. MODE 1: bf16 out scaled by qscale (Q proj).
// MODE 2: bf16 out transposed per-head -> Vt[b][h][hd][t]. MODE 3: f32 out.
// ---------------------------------------------------------------------------
template <int TIN_BYTES, int MODE, typename TOUT>
__device__ __forceinline__ void gemm_body(const void* __restrict__ Av,
                                          const float* __restrict__ W,
                                          const float* __restrict__ bias,
                                          TOUT* __restrict__ C,
                                          int K, int N) {
  __shared__ __align__(16) unsigned short sA[128 * 64];
  __shared__ __align__(16) unsigned short sB[128 * 64];
  const int tid = threadIdx.x;
  const int lane = tid & 63, wid = tid >> 6;
  const int wm = wid >> 1, wn = wid & 1;
  const int lr = lane & 15, lg = lane >> 4;
  const int bm = blockIdx.y * 128, bn = blockIdx.x * 128;
  const int srow = tid >> 1, shalf = (tid & 1) * 32;

  f32x4 acc[4][4] = {};

  for (int k0 = 0; k0 < K; k0 += 64) {
    if constexpr (TIN_BYTES == 4) {
      const float* src = (const float*)Av + (size_t)(bm + srow) * K + k0 + shalf;
#pragma unroll
      for (int u = 0; u < 8; ++u) {
        float4 f = *(const float4*)(src + u * 4);
        u16x4 h = { f2b(f.x), f2b(f.y), f2b(f.z), f2b(f.w) };
        int idx = (srow * 64 + shalf + u * 4) ^ ((srow & 7) << 3);
        *(u16x4*)(&sA[idx]) = h;
      }
    } else {
      const unsigned short* src = (const unsigned short*)Av + (size_t)(bm + srow) * K + k0 + shalf;
#pragma unroll
      for (int u = 0; u < 4; ++u) {
        u16x8 hv = *(const u16x8*)(src + u * 8);
        int idx = (srow * 64 + shalf + u * 8) ^ ((srow & 7) << 3);
        *(u16x8*)(&sA[idx]) = hv;
      }
    }
    {
      const float* src = W + (size_t)(bn + srow) * K + k0 + shalf;
#pragma unroll
      for (int u = 0; u < 8; ++u) {
        float4 f = *(const float4*)(src + u * 4);
        u16x4 h = { f2b(f.x), f2b(f.y), f2b(f.z), f2b(f.w) };
        int idx = (srow * 64 + shalf + u * 4) ^ ((srow & 7) << 3);
        *(u16x4*)(&sB[idx]) = h;
      }
    }
    __syncthreads();

    b16x8 af[4][2], bf[4][2];
#pragma unroll
    for (int mb = 0; mb < 4; ++mb)
#pragma unroll
      for (int kh = 0; kh < 2; ++kh) {
        int r = wm * 64 + mb * 16 + lr;
        int idx = (r * 64 + kh * 32 + lg * 8) ^ ((r & 7) << 3);
        af[mb][kh] = as_b(*(const u16x8*)(&sA[idx]));
      }
#pragma unroll
    for (int nb = 0; nb < 4; ++nb)
#pragma unroll
      for (int kh = 0; kh < 2; ++kh) {
        int r = wn * 64 + nb * 16 + lr;
        int idx = (r * 64 + kh * 32 + lg * 8) ^ ((r & 7) << 3);
        bf[nb][kh] = as_b(*(const u16x8*)(&sB[idx]));
      }
#pragma unroll
    for (int mb = 0; mb < 4; ++mb)
#pragma unroll
      for (int nb = 0; nb < 4; ++nb) {
        acc[mb][nb] = __builtin_amdgcn_mfma_f32_16x16x32_bf16(af[mb][0], bf[nb][0], acc[mb][nb], 0, 0, 0);
        acc[mb][nb] = __builtin_amdgcn_mfma_f32_16x16x32_bf16(af[mb][1], bf[nb][1], acc[mb][nb], 0, 0, 0);
      }
    __syncthreads();
  }

  const float qscale = 0.125f * 1.44269504f;   // fold 1/sqrt(64) * log2(e) into Q
#pragma unroll
  for (int mb = 0; mb < 4; ++mb)
#pragma unroll
    for (int nb = 0; nb < 4; ++nb) {
      int c = bn + wn * 64 + nb * 16 + lr;
      float bv = bias[c];
      int r0 = bm + wm * 64 + mb * 16 + lg * 4;
      if constexpr (MODE == 2) {
        // transposed per-head: Vt[((b*16+h)*64+hd)*2048 + t], 4 consecutive t
        int hh = c >> 6, hd = c & 63;
        int bb = r0 >> 11, t0 = r0 & 2047;
        u16x4 pk = { f2b(acc[mb][nb][0] + bv), f2b(acc[mb][nb][1] + bv),
                     f2b(acc[mb][nb][2] + bv), f2b(acc[mb][nb][3] + bv) };
        *(u16x4*)(&C[(((size_t)bb * 16 + hh) * 64 + hd) * 2048 + t0]) = pk;
      } else {
#pragma unroll
        for (int i = 0; i < 4; ++i) {
          float val = acc[mb][nb][i] + bv;
          if constexpr (MODE == 1) val *= qscale;
          if constexpr (MODE == 3) C[(size_t)(r0 + i) * N + c] = val;
          else                     C[(size_t)(r0 + i) * N + c] = (TOUT)f2b(val);
        }
      }
    }
}

__global__ __launch_bounds__(256) void proj_kernel(
    const float* __restrict__ q, const float* __restrict__ k, const float* __restrict__ v,
    const float* __restrict__ Wq, const float* __restrict__ bq,
    const float* __restrict__ Wk, const float* __restrict__ bk,
    const float* __restrict__ Wv, const float* __restrict__ bv,
    unsigned short* __restrict__ Qh, unsigned short* __restrict__ Kh,
    unsigned short* __restrict__ Vt) {
  if (blockIdx.z == 0)      gemm_body<4, 1, unsigned short>(q, Wq, bq, Qh, 1024, 1024);
  else if (blockIdx.z == 1) gemm_body<4, 0, unsigned short>(k, Wk, bk, Kh, 1024, 1024);
  else                      gemm_body<4, 2, unsigned short>(v, Wv, bv, Vt, 1024, 1024);
}

__global__ __launch_bounds__(256) void out_kernel(
    const unsigned short* __restrict__ X, const float* __restrict__ Wo,
    const float* __restrict__ bo, float* __restrict__ out) {
  gemm_body<2, 3, float>(X, Wo, bo, out, 1024, 1024);
}

// ---------------------------------------------------------------------------
// Flash attention, 32x32 swapped-operand structure.
// Grid (16, 32): 128 q-rows per block, 4 waves x 32 q-rows. KV tiles of 64,
// double-buffered in LDS via global_load_lds with pre-swizzled source.
// S^T = K*Q^T (q lane-local softmax), O^T = V^T*P (q lane-local rescale).
// ---------------------------------------------------------------------------
__global__ __launch_bounds__(256, 2) void attn_kernel(
    const unsigned short* __restrict__ Qh, const unsigned short* __restrict__ Kh,
    const unsigned short* __restrict__ Vt, unsigned short* __restrict__ X) {
  __shared__ __align__(16) unsigned short sK[2][64 * 64];
  __shared__ __align__(16) unsigned short sV[2][64 * 64];   // [hd][kv] from Vt

  const int tid = threadIdx.x;
  const int l = tid & 63, wq = tid >> 6;
  const int lq = l & 31, lg = l >> 5;
  const int b = blockIdx.y >> 4, h = blockIdx.y & 15;
  const int q0 = blockIdx.x * 128 + wq * 32;

  const size_t baseQK = (size_t)b * 2048 * 1024 + (size_t)h * 64;
  const size_t baseV  = ((size_t)(b * 16 + h)) * 64 * 2048;

  // Q fragments (B-operand): row q0+lq, elems hd = 16c + 8*lg + e. Direct global.
  b16x8 qf0, qf1, qf2, qf3;
  {
    const unsigned short* qp = Qh + baseQK + (size_t)(q0 + lq) * 1024 + 8 * lg;
    qf0 = as_b(*(const u16x8*)(qp));
    qf1 = as_b(*(const u16x8*)(qp + 16));
    qf2 = as_b(*(const u16x8*)(qp + 32));
    qf3 = as_b(*(const u16x8*)(qp + 48));
  }

  // staging geometry: wave stages rows [16*wq, 16*wq+16) of both K and V tiles.
  const int r8 = l >> 3, sl = l & 7;
  const int swz8 = (sl ^ r8) * 8;   // pre-swizzled source slot (row&7 == r8)

  auto stage = [&](int buf, int kv0) {
#pragma unroll
    for (int i = 0; i < 2; ++i) {
      const int rowb = 16 * wq + 8 * i;
      const unsigned short* gk = Kh + baseQK + (size_t)(kv0 + rowb + r8) * 1024 + swz8;
      gload_lds16(gk, &sK[buf][rowb * 64]);
      const unsigned short* gv = Vt + baseV + (size_t)(rowb + r8) * 2048 + kv0 + swz8;
      gload_lds16(gv, &sV[buf][rowb * 64]);
    }
  };

  float m_run = -1e30f, l_run = 0.f;
  f32x16 Oa = {}, Ob = {};

  stage(0, 0);
  __syncthreads();

  for (int t = 0; t < 32; ++t) {
    const int cur = t & 1;
    if (t + 1 < 32) stage(cur ^ 1, (t + 1) * 64);

    const unsigned short* K_ = sK[cur];
    const unsigned short* V_ = sV[cur];
    const int sw = (lq & 7) << 3;   // (row&7)<<3 for rows lq and 32+lq

    // S^T = K * Q^T  (rows kv, cols q = lane&31), scale pre-folded into Q
    f32x16 s0 = {}, s1 = {};
#pragma unroll
    for (int c = 0; c < 4; ++c) {
      const int hd8 = c * 16 + 8 * lg;
      b16x8 kf0 = as_b(*(const u16x8*)(&K_[lq * 64 + (hd8 ^ sw)]));
      b16x8 kf1 = as_b(*(const u16x8*)(&K_[(32 + lq) * 64 + (hd8 ^ sw)]));
      b16x8 qf = (c == 0) ? qf0 : (c == 1) ? qf1 : (c == 2) ? qf2 : qf3;
      s0 = __builtin_amdgcn_mfma_f32_32x32x16_bf16(kf0, qf, s0, 0, 0, 0);
      s1 = __builtin_amdgcn_mfma_f32_32x32x16_bf16(kf1, qf, s1, 0, 0, 0);
    }

    // online softmax, fully lane-local per q (+1 shfl pair with lane^32)
    float mx = s0[0];
#pragma unroll
    for (int j = 1; j < 16; ++j) mx = fmaxf(mx, s0[j]);
#pragma unroll
    for (int j = 0; j < 16; ++j) mx = fmaxf(mx, s1[j]);
    mx = fmaxf(mx, __shfl_xor(mx, 32));
    const float mnew = fmaxf(m_run, mx);
    const float al = fexp2(m_run - mnew);
    m_run = mnew;
    float rs = 0.f;
#pragma unroll
    for (int j = 0; j < 16; ++j) { s0[j] = fexp2(s0[j] - mnew); rs += s0[j]; }
#pragma unroll
    for (int j = 0; j < 16; ++j) { s1[j] = fexp2(s1[j] - mnew); rs += s1[j]; }
    rs += __shfl_xor(rs, 32);
    l_run = l_run * al + rs;
#pragma unroll
    for (int j = 0; j < 16; ++j) { Oa[j] *= al; Ob[j] *= al; }

    // P fragments: kv chunks of 16 (c = 0..3)
    b16x8 pb0 = mkchunk(s0[0], s0[1], s0[2], s0[3], s0[4], s0[5], s0[6], s0[7]);
    b16x8 pb1 = mkchunk(s0[8], s0[9], s0[10], s0[11], s0[12], s0[13], s0[14], s0[15]);
    b16x8 pb2 = mkchunk(s1[0], s1[1], s1[2], s1[3], s1[4], s1[5], s1[6], s1[7]);
    b16x8 pb3 = mkchunk(s1[8], s1[9], s1[10], s1[11], s1[12], s1[13], s1[14], s1[15]);

    // O^T += V^T * P  (rows hd, cols q = lane&31)
#pragma unroll
    for (int c = 0; c < 4; ++c) {
      const int kv8 = c * 16 + 8 * lg;
      b16x8 vfa = as_b(*(const u16x8*)(&V_[lq * 64 + (kv8 ^ sw)]));
      b16x8 vfb = as_b(*(const u16x8*)(&V_[(32 + lq) * 64 + (kv8 ^ sw)]));
      b16x8 pb = (c == 0) ? pb0 : (c == 1) ? pb1 : (c == 2) ? pb2 : pb3;
      Oa = __builtin_amdgcn_mfma_f32_32x32x16_bf16(vfa, pb, Oa, 0, 0, 0);
      Ob = __builtin_amdgcn_mfma_f32_32x32x16_bf16(vfb, pb, Ob, 0, 0, 0);
    }
    __syncthreads();
  }

  // epilogue: lane owns q = q0+lq entirely; hd = 32*o + 8*g + 4*lg + i
  const float inv = 1.0f / l_run;
  unsigned short* xp = X + baseQK + (size_t)(q0 + lq) * 1024;
#pragma unroll
  for (int g = 0; g < 4; ++g) {
    u16x4 wa = { f2b(Oa[4 * g + 0] * inv), f2b(Oa[4 * g + 1] * inv),
                 f2b(Oa[4 * g + 2] * inv), f2b(Oa[4 * g + 3] * inv) };
    *(u16x4*)(xp + 8 * g + 4 * lg) = wa;
    u16x4 wb = { f2b(Ob[4 * g + 0] * inv), f2b(Ob[4 * g + 1] * inv),
                 f2b(Ob[4 * g + 2] * inv), f2b(Ob[4 * g + 3] * inv) };
    *(u16x4*)(xp + 32 + 8 * g + 4 * lg) = wb;
  }
}

extern "C" void kernel_launch(void* const* d_in, const int* in_sizes, int n_in,
                              void* d_out, int out_size, void* d_ws, size_t ws_size,
                              hipStream_t stream) {
  const float* q  = (const float*)d_in[0];
  const float* k  = (const float*)d_in[1];
  const float* v  = (const float*)d_in[2];
  const float* Wq = (const float*)d_in[3];
  const float* bq = (const float*)d_in[4];
  const float* Wk = (const float*)d_in[5];
  const float* bk = (const float*)d_in[6];
  const float* Wv = (const float*)d_in[7];
  const float* bv = (const float*)d_in[8];
  const float* Wo = (const float*)d_in[9];
  const float* bo = (const float*)d_in[10];

  unsigned short* Qh = (unsigned short*)d_ws;
  unsigned short* Kh = Qh + (size_t)4096 * 1024;
  unsigned short* Vt = Kh + (size_t)4096 * 1024;
  unsigned short* X  = Vt + (size_t)4096 * 1024;

  dim3 blk(256);
  proj_kernel<<<dim3(8, 32, 3), blk, 0, stream>>>(q, k, v, Wq, bq, Wk, bk, Wv, bv, Qh, Kh, Vt);
  attn_kernel<<<dim3(16, 32), blk, 0, stream>>>(Qh, Kh, Vt, X);
  out_kernel<<<dim3(8, 32), blk, 0, stream>>>(X, Wo, bo, (float*)d_out);
}

// Round 4
// 143.552 us; speedup vs baseline: 2.0921x; 1.7563x over previous
//
#include <hip/hip_runtime.h>
#include <hip/hip_bf16.h>

typedef __bf16 b16x8 __attribute__((ext_vector_type(8)));
typedef unsigned short u16x8 __attribute__((ext_vector_type(8)));
typedef unsigned short u16x4 __attribute__((ext_vector_type(4)));
typedef unsigned int u32x4 __attribute__((ext_vector_type(4)));
typedef float f32x4 __attribute__((ext_vector_type(4)));
typedef float f32x16 __attribute__((ext_vector_type(16)));

__device__ __forceinline__ unsigned short f2b(float f) {
  unsigned u = __builtin_bit_cast(unsigned, f);
  u += 0x7fff + ((u >> 16) & 1);   // round-to-nearest-even
  return (unsigned short)(u >> 16);
}

__device__ __forceinline__ b16x8 as_b(u16x8 v) { return __builtin_bit_cast(b16x8, v); }

__device__ __forceinline__ float fexp2(float x) {
#if __has_builtin(__builtin_amdgcn_exp2f)
  return __builtin_amdgcn_exp2f(x);
#else
  return exp2f(x);
#endif
}

__device__ __forceinline__ unsigned pk2(float lo, float hi) {
  return (unsigned)f2b(lo) | ((unsigned)f2b(hi) << 16);
}

__device__ __forceinline__ void plswap(unsigned& a, unsigned& b) {
  asm volatile("v_permlane32_swap_b32 %0, %1" : "+v"(a), "+v"(b));
}

// P-fragment redistribution (see round-2 derivation), unchanged.
__device__ __forceinline__ b16x8 mkchunk(float p0, float p1, float p2, float p3,
                                         float p4, float p5, float p6, float p7) {
  unsigned a1 = pk2(p0, p1), b1 = pk2(p4, p5);
  unsigned a2 = pk2(p2, p3), b2 = pk2(p6, p7);
  plswap(a1, b1);
  plswap(a2, b2);
  u32x4 w = {a1, a2, b1, b2};
  return __builtin_bit_cast(b16x8, w);
}

#define AS1 __attribute__((address_space(1)))
#define AS3 __attribute__((address_space(3)))
__device__ __forceinline__ void gload_lds16(const void* g, void* l) {
  __builtin_amdgcn_global_load_lds((const AS1 void*)g, (AS3 void*)l, 16, 0, 0);
}

// Global pre-swizzle convention for bf16 matrices with row length a multiple
// of 64: within each 64-elem chunk, 16B slot s holds the data of slot
// s ^ (row & 7). global_load_lds with LINEAR source+dest then yields the
// XOR-swizzled LDS layout; ds_read applies idx ^= (row&7)<<3.

// ---------------------------------------------------------------------------
// convert: fp32 [rows][1024] -> bf16 pre-swizzled. grid (2048, 7).
// ---------------------------------------------------------------------------
__global__ __launch_bounds__(256) void convert_kernel(
    const float* __restrict__ q, const float* __restrict__ k, const float* __restrict__ v,
    const float* __restrict__ Wq, const float* __restrict__ Wk,
    const float* __restrict__ Wv, const float* __restrict__ Wo,
    unsigned short* __restrict__ qb, unsigned short* __restrict__ kb,
    unsigned short* __restrict__ vb, unsigned short* __restrict__ wqb,
    unsigned short* __restrict__ wkb, unsigned short* __restrict__ wvb,
    unsigned short* __restrict__ wob) {
  const float* src; unsigned short* dst; int rows;
  switch (blockIdx.y) {
    case 0: src = q;  dst = qb;  rows = 4096; break;
    case 1: src = k;  dst = kb;  rows = 4096; break;
    case 2: src = v;  dst = vb;  rows = 4096; break;
    case 3: src = Wq; dst = wqb; rows = 1024; break;
    case 4: src = Wk; dst = wkb; rows = 1024; break;
    case 5: src = Wv; dst = wvb; rows = 1024; break;
    default: src = Wo; dst = wob; rows = 1024; break;
  }
  const int row = blockIdx.x * 2 + (threadIdx.x >> 7);
  if (row >= rows) return;
  const int t = threadIdx.x & 127;
  const float* sp = src + (size_t)row * 1024 + t * 8;
  float4 f0 = *(const float4*)sp;
  float4 f1 = *(const float4*)(sp + 4);
  u16x8 h = { f2b(f0.x), f2b(f0.y), f2b(f0.z), f2b(f0.w),
              f2b(f1.x), f2b(f1.y), f2b(f1.z), f2b(f1.w) };
  const int swcol = ((t >> 3) << 6) | (((t & 7) ^ (row & 7)) << 3);
  *(u16x8*)(dst + (size_t)row * 1024 + swcol) = h;
}

// ---------------------------------------------------------------------------
// GEMM: C[M][1024] = A[M][1024] * W[1024][1024]^T + bias. BM=64, BN=128, BK=64.
// Both operands pre-swizzled bf16, staged via global_load_lds (linear).
// MODE 0: bf16 pre-swz out. MODE 1: +qscale. MODE 2: Vt transposed out.
// MODE 3: fp32 natural out.
// ---------------------------------------------------------------------------
template <int MODE, typename TOUT>
__device__ __forceinline__ void gemm_body(unsigned short* sA, unsigned short* sB,
                                          const unsigned short* __restrict__ A,
                                          const unsigned short* __restrict__ Bm,
                                          const float* __restrict__ bias,
                                          TOUT* __restrict__ C) {
  const int tid = threadIdx.x;
  const int l = tid & 63, w = tid >> 6;
  const int wm = w >> 1, wn = w & 1;
  const int lr = l & 15, lg = l >> 4;
  const int bm = blockIdx.y * 64, bn = blockIdx.x * 128;
  const int r8 = l >> 3, sl = l & 7;

  f32x4 acc[2][4] = {};

  for (int k0 = 0; k0 < 1024; k0 += 64) {
#pragma unroll
    for (int i = 0; i < 2; ++i) {
      const int row = i * 32 + w * 8 + r8;
      gload_lds16(A + (size_t)(bm + row) * 1024 + k0 + sl * 8, &sA[i * 2048 + w * 512]);
    }
#pragma unroll
    for (int i = 0; i < 4; ++i) {
      const int row = i * 32 + w * 8 + r8;
      gload_lds16(Bm + (size_t)(bn + row) * 1024 + k0 + sl * 8, &sB[i * 2048 + w * 512]);
    }
    __syncthreads();

    b16x8 af[2][2], bf[4][2];
#pragma unroll
    for (int mb = 0; mb < 2; ++mb)
#pragma unroll
      for (int kh = 0; kh < 2; ++kh) {
        const int r = wm * 32 + mb * 16 + lr;
        af[mb][kh] = as_b(*(const u16x8*)(&sA[(r * 64 + kh * 32 + lg * 8) ^ ((r & 7) << 3)]));
      }
#pragma unroll
    for (int nb = 0; nb < 4; ++nb)
#pragma unroll
      for (int kh = 0; kh < 2; ++kh) {
        const int r = wn * 64 + nb * 16 + lr;
        bf[nb][kh] = as_b(*(const u16x8*)(&sB[(r * 64 + kh * 32 + lg * 8) ^ ((r & 7) << 3)]));
      }
#pragma unroll
    for (int mb = 0; mb < 2; ++mb)
#pragma unroll
      for (int nb = 0; nb < 4; ++nb) {
        acc[mb][nb] = __builtin_amdgcn_mfma_f32_16x16x32_bf16(af[mb][0], bf[nb][0], acc[mb][nb], 0, 0, 0);
        acc[mb][nb] = __builtin_amdgcn_mfma_f32_16x16x32_bf16(af[mb][1], bf[nb][1], acc[mb][nb], 0, 0, 0);
      }
    __syncthreads();
  }

  const float qscale = 0.125f * 1.44269504f;
#pragma unroll
  for (int mb = 0; mb < 2; ++mb)
#pragma unroll
    for (int nb = 0; nb < 4; ++nb) {
      const int c = bn + wn * 64 + nb * 16 + lr;
      const float bv = bias[c];
      const int r0 = bm + wm * 32 + mb * 16 + lg * 4;
      if constexpr (MODE == 2) {
        const int hh = c >> 6, hd = c & 63;
        const int bb = r0 >> 11, t0 = r0 & 2047;
        u16x4 pk = { f2b(acc[mb][nb][0] + bv), f2b(acc[mb][nb][1] + bv),
                     f2b(acc[mb][nb][2] + bv), f2b(acc[mb][nb][3] + bv) };
        const int tsw = (t0 & ~63) | (((((t0 >> 3) & 7) ^ (hd & 7)) << 3)) | (t0 & 7);
        *(u16x4*)(&C[(((size_t)bb * 16 + hh) * 64 + hd) * 2048 + tsw]) = pk;
      } else {
#pragma unroll
        for (int i = 0; i < 4; ++i) {
          float val = acc[mb][nb][i] + bv;
          if constexpr (MODE == 1) val *= qscale;
          if constexpr (MODE == 3) {
            C[(size_t)(r0 + i) * 1024 + c] = val;
          } else {
            const int cc = (c & ~63) | (((((c >> 3) & 7) ^ ((r0 + i) & 7)) << 3)) | (c & 7);
            C[(size_t)(r0 + i) * 1024 + cc] = (TOUT)f2b(val);
          }
        }
      }
    }
}

__global__ __launch_bounds__(256) void proj_kernel(
    const unsigned short* __restrict__ qb, const unsigned short* __restrict__ kb,
    const unsigned short* __restrict__ vb,
    const unsigned short* __restrict__ wqb, const float* __restrict__ bq,
    const unsigned short* __restrict__ wkb, const float* __restrict__ bk,
    const unsigned short* __restrict__ wvb, const float* __restrict__ bv,
    unsigned short* __restrict__ Qh, unsigned short* __restrict__ Kh,
    unsigned short* __restrict__ Vt) {
  __shared__ __align__(16) unsigned short sA[64 * 64];
  __shared__ __align__(16) unsigned short sB[128 * 64];
  if (blockIdx.z == 0)      gemm_body<1, unsigned short>(sA, sB, qb, wqb, bq, Qh);
  else if (blockIdx.z == 1) gemm_body<0, unsigned short>(sA, sB, kb, wkb, bk, Kh);
  else                      gemm_body<2, unsigned short>(sA, sB, vb, wvb, bv, Vt);
}

__global__ __launch_bounds__(256) void out_kernel(
    const unsigned short* __restrict__ X, const unsigned short* __restrict__ wob,
    const float* __restrict__ bo, float* __restrict__ out) {
  __shared__ __align__(16) unsigned short sA[64 * 64];
  __shared__ __align__(16) unsigned short sB[128 * 64];
  gemm_body<3, float>(sA, sB, X, wob, bo, out);
}

// ---------------------------------------------------------------------------
// Flash attention, 32x32 swapped-operand structure (round-3, adapted to the
// pre-swizzled global layout: stage sources are now linear).
// ---------------------------------------------------------------------------
__global__ __launch_bounds__(256, 2) void attn_kernel(
    const unsigned short* __restrict__ Qh, const unsigned short* __restrict__ Kh,
    const unsigned short* __restrict__ Vt, unsigned short* __restrict__ X) {
  __shared__ __align__(16) unsigned short sK[2][64 * 64];
  __shared__ __align__(16) unsigned short sV[2][64 * 64];

  const int tid = threadIdx.x;
  const int l = tid & 63, wq = tid >> 6;
  const int lq = l & 31, lg = l >> 5;
  const int b = blockIdx.y >> 4, h = blockIdx.y & 15;
  const int q0 = blockIdx.x * 128 + wq * 32;

  const size_t baseQK = (size_t)b * 2048 * 1024 + (size_t)h * 64;
  const size_t baseV  = ((size_t)(b * 16 + h)) * 64 * 2048;

  // Q fragments from pre-swizzled Qh: elem hd = c*16 + 8*lg + e -> chunk 2c+lg.
  const int rk = lq & 7;   // (q0+lq)&7, q0 multiple of 32
  b16x8 qf0, qf1, qf2, qf3;
  {
    const unsigned short* qp = Qh + baseQK + (size_t)(q0 + lq) * 1024;
    qf0 = as_b(*(const u16x8*)(qp + (((0 + lg) ^ rk) << 3)));
    qf1 = as_b(*(const u16x8*)(qp + (((2 + lg) ^ rk) << 3)));
    qf2 = as_b(*(const u16x8*)(qp + (((4 + lg) ^ rk) << 3)));
    qf3 = as_b(*(const u16x8*)(qp + (((6 + lg) ^ rk) << 3)));
  }

  const int r8 = l >> 3, sl = l & 7;

  auto stage = [&](int buf, int kv0) {
#pragma unroll
    for (int i = 0; i < 2; ++i) {
      const int rowb = 16 * wq + 8 * i;
      gload_lds16(Kh + baseQK + (size_t)(kv0 + rowb + r8) * 1024 + sl * 8, &sK[buf][rowb * 64]);
      gload_lds16(Vt + baseV + (size_t)(rowb + r8) * 2048 + kv0 + sl * 8, &sV[buf][rowb * 64]);
    }
  };

  float m_run = -1e30f, l_run = 0.f;
  f32x16 Oa = {}, Ob = {};

  stage(0, 0);
  __syncthreads();

  for (int t = 0; t < 32; ++t) {
    const int cur = t & 1;
    if (t + 1 < 32) stage(cur ^ 1, (t + 1) * 64);

    const unsigned short* K_ = sK[cur];
    const unsigned short* V_ = sV[cur];
    const int sw = (lq & 7) << 3;

    f32x16 s0 = {}, s1 = {};
#pragma unroll
    for (int c = 0; c < 4; ++c) {
      const int hd8 = c * 16 + 8 * lg;
      b16x8 kf0 = as_b(*(const u16x8*)(&K_[lq * 64 + (hd8 ^ sw)]));
      b16x8 kf1 = as_b(*(const u16x8*)(&K_[(32 + lq) * 64 + (hd8 ^ sw)]));
      b16x8 qf = (c == 0) ? qf0 : (c == 1) ? qf1 : (c == 2) ? qf2 : qf3;
      s0 = __builtin_amdgcn_mfma_f32_32x32x16_bf16(kf0, qf, s0, 0, 0, 0);
      s1 = __builtin_amdgcn_mfma_f32_32x32x16_bf16(kf1, qf, s1, 0, 0, 0);
    }

    float mx = s0[0];
#pragma unroll
    for (int j = 1; j < 16; ++j) mx = fmaxf(mx, s0[j]);
#pragma unroll
    for (int j = 0; j < 16; ++j) mx = fmaxf(mx, s1[j]);
    mx = fmaxf(mx, __shfl_xor(mx, 32));
    const float mnew = fmaxf(m_run, mx);
    const float al = fexp2(m_run - mnew);
    m_run = mnew;
    float rs = 0.f;
#pragma unroll
    for (int j = 0; j < 16; ++j) { s0[j] = fexp2(s0[j] - mnew); rs += s0[j]; }
#pragma unroll
    for (int j = 0; j < 16; ++j) { s1[j] = fexp2(s1[j] - mnew); rs += s1[j]; }
    rs += __shfl_xor(rs, 32);
    l_run = l_run * al + rs;
#pragma unroll
    for (int j = 0; j < 16; ++j) { Oa[j] *= al; Ob[j] *= al; }

    b16x8 pb0 = mkchunk(s0[0], s0[1], s0[2], s0[3], s0[4], s0[5], s0[6], s0[7]);
    b16x8 pb1 = mkchunk(s0[8], s0[9], s0[10], s0[11], s0[12], s0[13], s0[14], s0[15]);
    b16x8 pb2 = mkchunk(s1[0], s1[1], s1[2], s1[3], s1[4], s1[5], s1[6], s1[7]);
    b16x8 pb3 = mkchunk(s1[8], s1[9], s1[10], s1[11], s1[12], s1[13], s1[14], s1[15]);

#pragma unroll
    for (int c = 0; c < 4; ++c) {
      const int kv8 = c * 16 + 8 * lg;
      b16x8 vfa = as_b(*(const u16x8*)(&V_[lq * 64 + (kv8 ^ sw)]));
      b16x8 vfb = as_b(*(const u16x8*)(&V_[(32 + lq) * 64 + (kv8 ^ sw)]));
      b16x8 pb = (c == 0) ? pb0 : (c == 1) ? pb1 : (c == 2) ? pb2 : pb3;
      Oa = __builtin_amdgcn_mfma_f32_32x32x16_bf16(vfa, pb, Oa, 0, 0, 0);
      Ob = __builtin_amdgcn_mfma_f32_32x32x16_bf16(vfb, pb, Ob, 0, 0, 0);
    }
    __syncthreads();
  }

  // epilogue: pre-swizzled X write. hd = 32*o + 8*g + 4*lg + i -> chunk 4o+g.
  const float inv = 1.0f / l_run;
  unsigned short* xp = X + baseQK + (size_t)(q0 + lq) * 1024;
#pragma unroll
  for (int g = 0; g < 4; ++g) {
    u16x4 wa = { f2b(Oa[4 * g + 0] * inv), f2b(Oa[4 * g + 1] * inv),
                 f2b(Oa[4 * g + 2] * inv), f2b(Oa[4 * g + 3] * inv) };
    *(u16x4*)(xp + ((g ^ rk) << 3) + 4 * lg) = wa;
    u16x4 wb = { f2b(Ob[4 * g + 0] * inv), f2b(Ob[4 * g + 1] * inv),
                 f2b(Ob[4 * g + 2] * inv), f2b(Ob[4 * g + 3] * inv) };
    *(u16x4*)(xp + (((4 + g) ^ rk) << 3) + 4 * lg) = wb;
  }
}

extern "C" void kernel_launch(void* const* d_in, const int* in_sizes, int n_in,
                              void* d_out, int out_size, void* d_ws, size_t ws_size,
                              hipStream_t stream) {
  const float* q  = (const float*)d_in[0];
  const float* k  = (const float*)d_in[1];
  const float* v  = (const float*)d_in[2];
  const float* Wq = (const float*)d_in[3];
  const float* bq = (const float*)d_in[4];
  const float* Wk = (const float*)d_in[5];
  const float* bk = (const float*)d_in[6];
  const float* Wv = (const float*)d_in[7];
  const float* bv = (const float*)d_in[8];
  const float* Wo = (const float*)d_in[9];
  const float* bo = (const float*)d_in[10];

  unsigned short* ws = (unsigned short*)d_ws;
  const size_t M1 = (size_t)1024 * 1024;
  unsigned short* qb  = ws;              // 4M elems
  unsigned short* kb  = ws + 4 * M1;
  unsigned short* vb  = ws + 8 * M1;
  unsigned short* wqb = ws + 12 * M1;
  unsigned short* wkb = ws + 13 * M1;
  unsigned short* wvb = ws + 14 * M1;
  unsigned short* wob = ws + 15 * M1;
  unsigned short* Qh  = ws + 16 * M1;
  unsigned short* Kh  = ws + 20 * M1;
  unsigned short* Vt  = ws + 24 * M1;
  unsigned short* X   = qb;              // alias: qb dead after proj_kernel

  dim3 blk(256);
  convert_kernel<<<dim3(2048, 7), blk, 0, stream>>>(q, k, v, Wq, Wk, Wv, Wo,
                                                    qb, kb, vb, wqb, wkb, wvb, wob);
  proj_kernel<<<dim3(8, 64, 3), blk, 0, stream>>>(qb, kb, vb, wqb, bq, wkb, bk, wvb, bv,
                                                  Qh, Kh, Vt);
  attn_kernel<<<dim3(16, 32), blk, 0, stream>>>(Qh, Kh, Vt, X);
  out_kernel<<<dim3(8, 64), blk, 0, stream>>>(X, wob, bo, (float*)d_out);
}

// Round 5
// 137.954 us; speedup vs baseline: 2.1771x; 1.0406x over previous
//
#include <hip/hip_runtime.h>
#include <hip/hip_bf16.h>

typedef __bf16 b16x8 __attribute__((ext_vector_type(8)));
typedef unsigned short u16x8 __attribute__((ext_vector_type(8)));
typedef unsigned short u16x4 __attribute__((ext_vector_type(4)));
typedef unsigned int u32x4 __attribute__((ext_vector_type(4)));
typedef unsigned int u32x2 __attribute__((ext_vector_type(2)));
typedef float f32x4 __attribute__((ext_vector_type(4)));
typedef float f32x16 __attribute__((ext_vector_type(16)));

__device__ __forceinline__ unsigned short f2b(float f) {
  unsigned u = __builtin_bit_cast(unsigned, f);
  u += 0x7fff + ((u >> 16) & 1);   // round-to-nearest-even
  return (unsigned short)(u >> 16);
}

__device__ __forceinline__ b16x8 as_b(u16x8 v) { return __builtin_bit_cast(b16x8, v); }

__device__ __forceinline__ float fexp2(float x) {
#if __has_builtin(__builtin_amdgcn_exp2f)
  return __builtin_amdgcn_exp2f(x);
#else
  return exp2f(x);
#endif
}

// packed f32x2 -> bf16x2 (RNE), single instruction
__device__ __forceinline__ unsigned cvtpk(float lo, float hi) {
  unsigned r;
  asm("v_cvt_pk_bf16_f32 %0, %1, %2" : "=v"(r) : "v"(lo), "v"(hi));
  return r;
}

__device__ __forceinline__ void plswap(unsigned& a, unsigned& b) {
  asm volatile("v_permlane32_swap_b32 %0, %1" : "+v"(a), "+v"(b));
}

// P-fragment redistribution (round-2 derivation, numerically verified).
__device__ __forceinline__ b16x8 mkchunk(float p0, float p1, float p2, float p3,
                                         float p4, float p5, float p6, float p7) {
  unsigned a1 = cvtpk(p0, p1), b1 = cvtpk(p4, p5);
  unsigned a2 = cvtpk(p2, p3), b2 = cvtpk(p6, p7);
  plswap(a1, b1);
  plswap(a2, b2);
  u32x4 w = {a1, a2, b1, b2};
  return __builtin_bit_cast(b16x8, w);
}

#define AS1 __attribute__((address_space(1)))
#define AS3 __attribute__((address_space(3)))
__device__ __forceinline__ void gload_lds16(const void* g, void* l) {
  __builtin_amdgcn_global_load_lds((const AS1 void*)g, (AS3 void*)l, 16, 0, 0);
}

// Global pre-swizzle convention: within each 64-elem chunk of a row, 16B slot
// s holds data of slot s ^ (row & 7). global_load_lds (linear) reproduces the
// swizzled LDS layout; ds_read applies idx ^= (row&7)<<3.

// ---------------------------------------------------------------------------
// convert: fp32 [rows][1024] -> bf16 pre-swizzled. grid (2048, 7).
// ---------------------------------------------------------------------------
__global__ __launch_bounds__(256) void convert_kernel(
    const float* __restrict__ q, const float* __restrict__ k, const float* __restrict__ v,
    const float* __restrict__ Wq, const float* __restrict__ Wk,
    const float* __restrict__ Wv, const float* __restrict__ Wo,
    unsigned short* __restrict__ qb, unsigned short* __restrict__ kb,
    unsigned short* __restrict__ vb, unsigned short* __restrict__ wqb,
    unsigned short* __restrict__ wkb, unsigned short* __restrict__ wvb,
    unsigned short* __restrict__ wob) {
  const float* src; unsigned short* dst; int rows;
  switch (blockIdx.y) {
    case 0: src = q;  dst = qb;  rows = 4096; break;
    case 1: src = k;  dst = kb;  rows = 4096; break;
    case 2: src = v;  dst = vb;  rows = 4096; break;
    case 3: src = Wq; dst = wqb; rows = 1024; break;
    case 4: src = Wk; dst = wkb; rows = 1024; break;
    case 5: src = Wv; dst = wvb; rows = 1024; break;
    default: src = Wo; dst = wob; rows = 1024; break;
  }
  const int row = blockIdx.x * 2 + (threadIdx.x >> 7);
  if (row >= rows) return;
  const int t = threadIdx.x & 127;
  const float* sp = src + (size_t)row * 1024 + t * 8;
  float4 f0 = *(const float4*)sp;
  float4 f1 = *(const float4*)(sp + 4);
  u16x8 h = { f2b(f0.x), f2b(f0.y), f2b(f0.z), f2b(f0.w),
              f2b(f1.x), f2b(f1.y), f2b(f1.z), f2b(f1.w) };
  const int swcol = ((t >> 3) << 6) | (((t & 7) ^ (row & 7)) << 3);
  *(u16x8*)(dst + (size_t)row * 1024 + swcol) = h;
}

// ---------------------------------------------------------------------------
// GEMM: C[M][1024] = A[M][1024] * W[1024][1024]^T + bias. BM=64, BN=128, BK=64.
// ---------------------------------------------------------------------------
template <int MODE, typename TOUT>
__device__ __forceinline__ void gemm_body(unsigned short* sA, unsigned short* sB,
                                          const unsigned short* __restrict__ A,
                                          const unsigned short* __restrict__ Bm,
                                          const float* __restrict__ bias,
                                          TOUT* __restrict__ C) {
  const int tid = threadIdx.x;
  const int l = tid & 63, w = tid >> 6;
  const int wm = w >> 1, wn = w & 1;
  const int lr = l & 15, lg = l >> 4;
  const int bm = blockIdx.y * 64, bn = blockIdx.x * 128;
  const int r8 = l >> 3, sl = l & 7;

  f32x4 acc[2][4] = {};

  for (int k0 = 0; k0 < 1024; k0 += 64) {
#pragma unroll
    for (int i = 0; i < 2; ++i) {
      const int row = i * 32 + w * 8 + r8;
      gload_lds16(A + (size_t)(bm + row) * 1024 + k0 + sl * 8, &sA[i * 2048 + w * 512]);
    }
#pragma unroll
    for (int i = 0; i < 4; ++i) {
      const int row = i * 32 + w * 8 + r8;
      gload_lds16(Bm + (size_t)(bn + row) * 1024 + k0 + sl * 8, &sB[i * 2048 + w * 512]);
    }
    __syncthreads();

    b16x8 af[2][2], bf[4][2];
#pragma unroll
    for (int mb = 0; mb < 2; ++mb)
#pragma unroll
      for (int kh = 0; kh < 2; ++kh) {
        const int r = wm * 32 + mb * 16 + lr;
        af[mb][kh] = as_b(*(const u16x8*)(&sA[(r * 64 + kh * 32 + lg * 8) ^ ((r & 7) << 3)]));
      }
#pragma unroll
    for (int nb = 0; nb < 4; ++nb)
#pragma unroll
      for (int kh = 0; kh < 2; ++kh) {
        const int r = wn * 64 + nb * 16 + lr;
        bf[nb][kh] = as_b(*(const u16x8*)(&sB[(r * 64 + kh * 32 + lg * 8) ^ ((r & 7) << 3)]));
      }
#pragma unroll
    for (int mb = 0; mb < 2; ++mb)
#pragma unroll
      for (int nb = 0; nb < 4; ++nb) {
        acc[mb][nb] = __builtin_amdgcn_mfma_f32_16x16x32_bf16(af[mb][0], bf[nb][0], acc[mb][nb], 0, 0, 0);
        acc[mb][nb] = __builtin_amdgcn_mfma_f32_16x16x32_bf16(af[mb][1], bf[nb][1], acc[mb][nb], 0, 0, 0);
      }
    __syncthreads();
  }

  const float qscale = 0.125f * 1.44269504f;
#pragma unroll
  for (int mb = 0; mb < 2; ++mb)
#pragma unroll
    for (int nb = 0; nb < 4; ++nb) {
      const int c = bn + wn * 64 + nb * 16 + lr;
      const float bv = bias[c];
      const int r0 = bm + wm * 32 + mb * 16 + lg * 4;
      if constexpr (MODE == 2) {
        const int hh = c >> 6, hd = c & 63;
        const int bb = r0 >> 11, t0 = r0 & 2047;
        u16x4 pk = { f2b(acc[mb][nb][0] + bv), f2b(acc[mb][nb][1] + bv),
                     f2b(acc[mb][nb][2] + bv), f2b(acc[mb][nb][3] + bv) };
        const int tsw = (t0 & ~63) | (((((t0 >> 3) & 7) ^ (hd & 7)) << 3)) | (t0 & 7);
        *(u16x4*)(&C[(((size_t)bb * 16 + hh) * 64 + hd) * 2048 + tsw]) = pk;
      } else {
#pragma unroll
        for (int i = 0; i < 4; ++i) {
          float val = acc[mb][nb][i] + bv;
          if constexpr (MODE == 1) val *= qscale;
          if constexpr (MODE == 3) {
            C[(size_t)(r0 + i) * 1024 + c] = val;
          } else {
            const int cc = (c & ~63) | (((((c >> 3) & 7) ^ ((r0 + i) & 7)) << 3)) | (c & 7);
            C[(size_t)(r0 + i) * 1024 + cc] = (TOUT)f2b(val);
          }
        }
      }
    }
}

__global__ __launch_bounds__(256) void proj_kernel(
    const unsigned short* __restrict__ qb, const unsigned short* __restrict__ kb,
    const unsigned short* __restrict__ vb,
    const unsigned short* __restrict__ wqb, const float* __restrict__ bq,
    const unsigned short* __restrict__ wkb, const float* __restrict__ bk,
    const unsigned short* __restrict__ wvb, const float* __restrict__ bv,
    unsigned short* __restrict__ Qh, unsigned short* __restrict__ Kh,
    unsigned short* __restrict__ Vt) {
  __shared__ __align__(16) unsigned short sA[64 * 64];
  __shared__ __align__(16) unsigned short sB[128 * 64];
  if (blockIdx.z == 0)      gemm_body<1, unsigned short>(sA, sB, qb, wqb, bq, Qh);
  else if (blockIdx.z == 1) gemm_body<0, unsigned short>(sA, sB, kb, wkb, bk, Kh);
  else                      gemm_body<2, unsigned short>(sA, sB, vb, wvb, bv, Vt);
}

__global__ __launch_bounds__(256) void out_kernel(
    const unsigned short* __restrict__ X, const unsigned short* __restrict__ wob,
    const float* __restrict__ bo, float* __restrict__ out) {
  __shared__ __align__(16) unsigned short sA[64 * 64];
  __shared__ __align__(16) unsigned short sB[128 * 64];
  gemm_body<3, float>(sA, sB, X, wob, bo, out);
}

// ---------------------------------------------------------------------------
// Flash attention, 32x32 swapped-operand structure + cvt_pk packing,
// defer-max (THR=8 in exp2 domain), tree reductions, setprio.
// ---------------------------------------------------------------------------
__global__ __launch_bounds__(256, 2) void attn_kernel(
    const unsigned short* __restrict__ Qh, const unsigned short* __restrict__ Kh,
    const unsigned short* __restrict__ Vt, unsigned short* __restrict__ X) {
  __shared__ __align__(16) unsigned short sK[2][64 * 64];
  __shared__ __align__(16) unsigned short sV[2][64 * 64];

  const int tid = threadIdx.x;
  const int l = tid & 63, wq = tid >> 6;
  const int lq = l & 31, lg = l >> 5;
  const int b = blockIdx.y >> 4, h = blockIdx.y & 15;
  const int q0 = blockIdx.x * 128 + wq * 32;

  const size_t baseQK = (size_t)b * 2048 * 1024 + (size_t)h * 64;
  const size_t baseV  = ((size_t)(b * 16 + h)) * 64 * 2048;

  const int rk = lq & 7;
  b16x8 qf0, qf1, qf2, qf3;
  {
    const unsigned short* qp = Qh + baseQK + (size_t)(q0 + lq) * 1024;
    qf0 = as_b(*(const u16x8*)(qp + (((0 + lg) ^ rk) << 3)));
    qf1 = as_b(*(const u16x8*)(qp + (((2 + lg) ^ rk) << 3)));
    qf2 = as_b(*(const u16x8*)(qp + (((4 + lg) ^ rk) << 3)));
    qf3 = as_b(*(const u16x8*)(qp + (((6 + lg) ^ rk) << 3)));
  }

  const int r8 = l >> 3, sl = l & 7;

  auto stage = [&](int buf, int kv0) {
#pragma unroll
    for (int i = 0; i < 2; ++i) {
      const int rowb = 16 * wq + 8 * i;
      gload_lds16(Kh + baseQK + (size_t)(kv0 + rowb + r8) * 1024 + sl * 8, &sK[buf][rowb * 64]);
      gload_lds16(Vt + baseV + (size_t)(rowb + r8) * 2048 + kv0 + sl * 8, &sV[buf][rowb * 64]);
    }
  };

  float m_run = -1e30f, l_run = 0.f;
  f32x16 Oa = {}, Ob = {};

  stage(0, 0);
  __syncthreads();

  for (int t = 0; t < 32; ++t) {
    const int cur = t & 1;
    if (t + 1 < 32) stage(cur ^ 1, (t + 1) * 64);

    const unsigned short* K_ = sK[cur];
    const unsigned short* V_ = sV[cur];
    const int sw = (lq & 7) << 3;

    f32x16 s0 = {}, s1 = {};
    __builtin_amdgcn_s_setprio(1);
#pragma unroll
    for (int c = 0; c < 4; ++c) {
      const int hd8 = c * 16 + 8 * lg;
      b16x8 kf0 = as_b(*(const u16x8*)(&K_[lq * 64 + (hd8 ^ sw)]));
      b16x8 kf1 = as_b(*(const u16x8*)(&K_[(32 + lq) * 64 + (hd8 ^ sw)]));
      b16x8 qf = (c == 0) ? qf0 : (c == 1) ? qf1 : (c == 2) ? qf2 : qf3;
      s0 = __builtin_amdgcn_mfma_f32_32x32x16_bf16(kf0, qf, s0, 0, 0, 0);
      s1 = __builtin_amdgcn_mfma_f32_32x32x16_bf16(kf1, qf, s1, 0, 0, 0);
    }
    __builtin_amdgcn_s_setprio(0);

    // tree max (v_max3-friendly groupings)
    float a0 = fmaxf(fmaxf(s0[0], s0[1]), fmaxf(s0[2], s0[3]));
    float a1 = fmaxf(fmaxf(s0[4], s0[5]), fmaxf(s0[6], s0[7]));
    float a2 = fmaxf(fmaxf(s0[8], s0[9]), fmaxf(s0[10], s0[11]));
    float a3 = fmaxf(fmaxf(s0[12], s0[13]), fmaxf(s0[14], s0[15]));
    float a4 = fmaxf(fmaxf(s1[0], s1[1]), fmaxf(s1[2], s1[3]));
    float a5 = fmaxf(fmaxf(s1[4], s1[5]), fmaxf(s1[6], s1[7]));
    float a6 = fmaxf(fmaxf(s1[8], s1[9]), fmaxf(s1[10], s1[11]));
    float a7 = fmaxf(fmaxf(s1[12], s1[13]), fmaxf(s1[14], s1[15]));
    float mx = fmaxf(fmaxf(fmaxf(a0, a1), fmaxf(a2, a3)),
                     fmaxf(fmaxf(a4, a5), fmaxf(a6, a7)));
    mx = fmaxf(mx, __shfl_xor(mx, 32));

    // defer-max: rescale only when the running max grows by > 8 (exp2 domain)
    if (__any(mx > m_run + 8.0f)) {
      const float mnew = fmaxf(m_run, mx);
      const float al = fexp2(m_run - mnew);
      m_run = mnew;
      l_run *= al;
#pragma unroll
      for (int j = 0; j < 16; ++j) { Oa[j] *= al; Ob[j] *= al; }
    }

#pragma unroll
    for (int j = 0; j < 16; ++j) s0[j] = fexp2(s0[j] - m_run);
#pragma unroll
    for (int j = 0; j < 16; ++j) s1[j] = fexp2(s1[j] - m_run);

    // tree sum
    float r0 = ((s0[0] + s0[1]) + (s0[2] + s0[3])) + ((s0[4] + s0[5]) + (s0[6] + s0[7]));
    float r1 = ((s0[8] + s0[9]) + (s0[10] + s0[11])) + ((s0[12] + s0[13]) + (s0[14] + s0[15]));
    float r2 = ((s1[0] + s1[1]) + (s1[2] + s1[3])) + ((s1[4] + s1[5]) + (s1[6] + s1[7]));
    float r3 = ((s1[8] + s1[9]) + (s1[10] + s1[11])) + ((s1[12] + s1[13]) + (s1[14] + s1[15]));
    float rs = (r0 + r1) + (r2 + r3);
    rs += __shfl_xor(rs, 32);
    l_run += rs;

    b16x8 pb0 = mkchunk(s0[0], s0[1], s0[2], s0[3], s0[4], s0[5], s0[6], s0[7]);
    b16x8 pb1 = mkchunk(s0[8], s0[9], s0[10], s0[11], s0[12], s0[13], s0[14], s0[15]);
    b16x8 pb2 = mkchunk(s1[0], s1[1], s1[2], s1[3], s1[4], s1[5], s1[6], s1[7]);
    b16x8 pb3 = mkchunk(s1[8], s1[9], s1[10], s1[11], s1[12], s1[13], s1[14], s1[15]);

    __builtin_amdgcn_s_setprio(1);
#pragma unroll
    for (int c = 0; c < 4; ++c) {
      const int kv8 = c * 16 + 8 * lg;
      b16x8 vfa = as_b(*(const u16x8*)(&V_[lq * 64 + (kv8 ^ sw)]));
      b16x8 vfb = as_b(*(const u16x8*)(&V_[(32 + lq) * 64 + (kv8 ^ sw)]));
      b16x8 pb = (c == 0) ? pb0 : (c == 1) ? pb1 : (c == 2) ? pb2 : pb3;
      Oa = __builtin_amdgcn_mfma_f32_32x32x16_bf16(vfa, pb, Oa, 0, 0, 0);
      Ob = __builtin_amdgcn_mfma_f32_32x32x16_bf16(vfb, pb, Ob, 0, 0, 0);
    }
    __builtin_amdgcn_s_setprio(0);
    __syncthreads();
  }

  // epilogue: pre-swizzled X write via cvt_pk
  const float inv = 1.0f / l_run;
  unsigned short* xp = X + baseQK + (size_t)(q0 + lq) * 1024;
#pragma unroll
  for (int g = 0; g < 4; ++g) {
    u32x2 wa = { cvtpk(Oa[4 * g + 0] * inv, Oa[4 * g + 1] * inv),
                 cvtpk(Oa[4 * g + 2] * inv, Oa[4 * g + 3] * inv) };
    *(u32x2*)(xp + ((g ^ rk) << 3) + 4 * lg) = wa;
    u32x2 wb = { cvtpk(Ob[4 * g + 0] * inv, Ob[4 * g + 1] * inv),
                 cvtpk(Ob[4 * g + 2] * inv, Ob[4 * g + 3] * inv) };
    *(u32x2*)(xp + (((4 + g) ^ rk) << 3) + 4 * lg) = wb;
  }
}

extern "C" void kernel_launch(void* const* d_in, const int* in_sizes, int n_in,
                              void* d_out, int out_size, void* d_ws, size_t ws_size,
                              hipStream_t stream) {
  const float* q  = (const float*)d_in[0];
  const float* k  = (const float*)d_in[1];
  const float* v  = (const float*)d_in[2];
  const float* Wq = (const float*)d_in[3];
  const float* bq = (const float*)d_in[4];
  const float* Wk = (const float*)d_in[5];
  const float* bk = (const float*)d_in[6];
  const float* Wv = (const float*)d_in[7];
  const float* bv = (const float*)d_in[8];
  const float* Wo = (const float*)d_in[9];
  const float* bo = (const float*)d_in[10];

  unsigned short* ws = (unsigned short*)d_ws;
  const size_t M1 = (size_t)1024 * 1024;
  unsigned short* qb  = ws;
  unsigned short* kb  = ws + 4 * M1;
  unsigned short* vb  = ws + 8 * M1;
  unsigned short* wqb = ws + 12 * M1;
  unsigned short* wkb = ws + 13 * M1;
  unsigned short* wvb = ws + 14 * M1;
  unsigned short* wob = ws + 15 * M1;
  unsigned short* Qh  = ws + 16 * M1;
  unsigned short* Kh  = ws + 20 * M1;
  unsigned short* Vt  = ws + 24 * M1;
  unsigned short* X   = qb;              // alias: qb dead after proj_kernel

  dim3 blk(256);
  convert_kernel<<<dim3(2048, 7), blk, 0, stream>>>(q, k, v, Wq, Wk, Wv, Wo,
                                                    qb, kb, vb, wqb, wkb, wvb, wob);
  proj_kernel<<<dim3(8, 64, 3), blk, 0, stream>>>(qb, kb, vb, wqb, bq, wkb, bk, wvb, bv,
                                                  Qh, Kh, Vt);
  attn_kernel<<<dim3(16, 32), blk, 0, stream>>>(Qh, Kh, Vt, X);
  out_kernel<<<dim3(8, 64), blk, 0, stream>>>(X, wob, bo, (float*)d_out);
}